// Round 1
// baseline (356.215 us; speedup 1.0000x reference)
//
#include <hip/hip_runtime.h>
#include <hip/hip_bf16.h>
#include <cstdint>

// Problem constants (B,S,D,H) from the reference
#define B_ 64
#define S_ 2048
#define D_ 512
#define H_ 512

using f32x4  = __attribute__((ext_vector_type(4))) float;
using bf16x8 = __attribute__((ext_vector_type(8))) short;

__device__ __forceinline__ unsigned short f2bf(float f) {
  unsigned u = __float_as_uint(f);
  u += 0x7FFFu + ((u >> 16) & 1u);   // round-to-nearest-even
  return (unsigned short)(u >> 16);
}
__device__ __forceinline__ float bf2f(unsigned short h) {
  return __uint_as_float(((unsigned)h) << 16);
}
// tanh via v_exp_f32: 1 - 2/(exp2(2x*log2e)+1); exact saturation at +-inf
__device__ __forceinline__ float fast_tanh(float x) {
  float t = __builtin_amdgcn_exp2f(x * 2.8853900817779268f);
  return 1.0f - 2.0f * __builtin_amdgcn_rcpf(t + 1.0f);
}

// ---------------------------------------------------------------------------
// Mask dtype detection: if the harness passed bool as int32, bytes 4k+1..3 of
// the first 32768 words are all zero. Random 0/1 bytes (bool layout) are not.
// Reads only the first 128 KiB, valid under both interpretations.
// flag=0 -> int32 layout, flag=1 -> byte layout.
__global__ void k_detect(const unsigned int* __restrict__ mw, int* __restrict__ flag) {
  unsigned acc = 0;
  for (int k = threadIdx.x; k < (B_ * S_ / 4); k += 256)
    acc |= mw[k] & 0xFFFFFF00u;
  if (acc) atomicOr(flag, 1);
}

// ---------------------------------------------------------------------------
// di[b,h] = hidden[b,:] . Wd[h,:] + bd[h]   (fp32, tiny: 33 MFLOP)
// Mapping: lane = b (so the Wd row address is wave-uniform -> broadcast load)
__global__ void k_di(const float* __restrict__ hidden, const float* __restrict__ Wd,
                     const float* __restrict__ bd, float* __restrict__ di) {
  int idx = blockIdx.x * 256 + threadIdx.x;   // 32768 total
  int h = idx >> 6;
  int b = idx & 63;
  const f32x4* hp = (const f32x4*)(hidden + (size_t)b * D_);
  const f32x4* wp = (const f32x4*)(Wd + (size_t)h * D_);
  float acc = 0.f;
#pragma unroll 8
  for (int i = 0; i < D_ / 4; ++i) {
    f32x4 x = hp[i], y = wp[i];
    acc += x[0] * y[0] + x[1] * y[1] + x[2] * y[2] + x[3] * y[3];
  }
  di[b * H_ + h] = acc + bd[h];
}

// ---------------------------------------------------------------------------
// ei[m, n] = context[m, :] . We[n, :] + be[n], stored as bf16 in ws.
// M = B*S = 131072, N = 512, K = 512. bf16 MFMA 16x16x32, fp32 accumulate.
// Block: 256 threads (4 waves, 2x2), tile BM=128 x BN=128, BK=32.
// n-outer loop per block so each A-panel is read from HBM exactly once
// (re-reads of the 256 KB panel across the 4 n-tiles hit L2).
#define BM 128
#define BN 128
#define BK 32
#define LDK 40   // padded LDS row stride in bf16 elems (80 B, 16B-aligned, ~2-way banks)

__device__ __forceinline__ void store8(unsigned short* p, f32x4 a, f32x4 b) {
  bf16x8 o;
  o[0] = (short)f2bf(a[0]); o[1] = (short)f2bf(a[1]);
  o[2] = (short)f2bf(a[2]); o[3] = (short)f2bf(a[3]);
  o[4] = (short)f2bf(b[0]); o[5] = (short)f2bf(b[1]);
  o[6] = (short)f2bf(b[2]); o[7] = (short)f2bf(b[3]);
  *(bf16x8*)p = o;
}

__global__ __launch_bounds__(256, 2) void k_ei_gemm(
    const float* __restrict__ ctx, const float* __restrict__ We,
    const float* __restrict__ be, unsigned short* __restrict__ ei) {
  __shared__ unsigned short ldsA[BM * LDK];
  __shared__ unsigned short ldsB[BN * LDK];

  const int t = threadIdx.x;
  const int row0 = blockIdx.x * BM;

  // staging coords: chunks c = t and t+256; r = c>>2, kq = (c&3)*8
  const int r1 = t >> 2;
  const int kq = (t & 3) << 3;

  // wave/lane coords
  const int l  = t & 63;
  const int w  = t >> 6;
  const int wm = (w >> 1) * 64;
  const int wn = (w & 1) * 64;
  const int lr = l & 15;
  const int lg = l >> 4;

  unsigned short* wrA1 = &ldsA[r1 * LDK + kq];
  unsigned short* wrA2 = &ldsA[(r1 + 64) * LDK + kq];
  unsigned short* wrB1 = &ldsB[r1 * LDK + kq];
  unsigned short* wrB2 = &ldsB[(r1 + 64) * LDK + kq];

  const float* gA1 = ctx + (size_t)(row0 + r1) * D_ + kq;
  const float* gA2 = gA1 + (size_t)64 * D_;

  for (int nt = 0; nt < 4; ++nt) {
    const int col0 = nt * BN;
    const float* gB1 = We + (size_t)(col0 + r1) * D_ + kq;
    const float* gB2 = gB1 + (size_t)64 * D_;

    f32x4 acc[4][4];
    const f32x4 z = {0.f, 0.f, 0.f, 0.f};
#pragma unroll
    for (int mi = 0; mi < 4; ++mi)
#pragma unroll
      for (int ni = 0; ni < 4; ++ni) acc[mi][ni] = z;

    for (int kt = 0; kt < D_ / BK; ++kt) {
      const int k0 = kt * BK;
      __syncthreads();
      {
        f32x4 a0 = *(const f32x4*)(gA1 + k0);
        f32x4 a1 = *(const f32x4*)(gA1 + k0 + 4);
        f32x4 a2 = *(const f32x4*)(gA2 + k0);
        f32x4 a3 = *(const f32x4*)(gA2 + k0 + 4);
        f32x4 b0 = *(const f32x4*)(gB1 + k0);
        f32x4 b1 = *(const f32x4*)(gB1 + k0 + 4);
        f32x4 b2 = *(const f32x4*)(gB2 + k0);
        f32x4 b3 = *(const f32x4*)(gB2 + k0 + 4);
        store8(wrA1, a0, a1);
        store8(wrA2, a2, a3);
        store8(wrB1, b0, b1);
        store8(wrB2, b2, b3);
      }
      __syncthreads();

      bf16x8 af[4], bfr[4];
#pragma unroll
      for (int mi = 0; mi < 4; ++mi)
        af[mi] = *(const bf16x8*)&ldsA[(wm + mi * 16 + lr) * LDK + lg * 8];
#pragma unroll
      for (int ni = 0; ni < 4; ++ni)
        bfr[ni] = *(const bf16x8*)&ldsB[(wn + ni * 16 + lr) * LDK + lg * 8];
#pragma unroll
      for (int mi = 0; mi < 4; ++mi)
#pragma unroll
        for (int ni = 0; ni < 4; ++ni)
          acc[mi][ni] = __builtin_amdgcn_mfma_f32_16x16x32_bf16(
              af[mi], bfr[ni], acc[mi][ni], 0, 0, 0);
    }

    // epilogue: +be, store bf16. C/D layout: col = lane&15, row = (lane>>4)*4+j
#pragma unroll
    for (int ni = 0; ni < 4; ++ni) {
      const int gc = col0 + wn + ni * 16 + lr;
      const float bev = be[gc];
#pragma unroll
      for (int mi = 0; mi < 4; ++mi) {
#pragma unroll
        for (int j = 0; j < 4; ++j) {
          const int gr = row0 + wm + mi * 16 + lg * 4 + j;
          ei[(size_t)gr * H_ + gc] = f2bf(acc[mi][ni][j] + bev);
        }
      }
    }
  }
}

// ---------------------------------------------------------------------------
// ui[b,s] = sum_h V[h] * tanh(di[b,h] + ei[b,s,h]); masked -> -inf
// One wave per (b,s) row; lane l covers h = 8l..8l+7 (16B bf16 loads).
__global__ void k_ui(const unsigned short* __restrict__ ei, const float* __restrict__ di,
                     const float* __restrict__ V, const void* __restrict__ mask,
                     const int* __restrict__ flag, float* __restrict__ ui) {
  const int row = blockIdx.x * 4 + (threadIdx.x >> 6);
  const int l = threadIdx.x & 63;
  const int b = row >> 11;
  const int h0 = l << 3;

  bf16x8 e = *(const bf16x8*)(ei + (size_t)row * H_ + h0);
  const f32x4* dp = (const f32x4*)(di + b * H_ + h0);
  const f32x4* vp = (const f32x4*)(V + h0);
  f32x4 d0 = dp[0], d1 = dp[1];
  f32x4 v0 = vp[0], v1 = vp[1];

  float s = 0.f;
#pragma unroll
  for (int j = 0; j < 4; ++j) s += v0[j] * fast_tanh(d0[j] + bf2f((unsigned short)e[j]));
#pragma unroll
  for (int j = 0; j < 4; ++j) s += v1[j] * fast_tanh(d1[j] + bf2f((unsigned short)e[4 + j]));

#pragma unroll
  for (int off = 32; off; off >>= 1) s += __shfl_xor(s, off);

  if (l == 0) {
    int m = (*flag) ? (int)((const unsigned char*)mask)[row]
                    : ((const int*)mask)[row];
    ui[row] = m ? -__builtin_inff() : s;
  }
}

// ---------------------------------------------------------------------------
// softmax over S per batch row: alpha[b,s] = exp(ui-m)/l
__global__ void k_softmax(const float* __restrict__ ui, float* __restrict__ alpha) {
  __shared__ float red[4];
  const int b = blockIdx.x, t = threadIdx.x;
  const int l = t & 63, w = t >> 6;

  float u[8];
#pragma unroll
  for (int i = 0; i < 8; ++i) u[i] = ui[b * S_ + t + i * 256];

  float m = u[0];
#pragma unroll
  for (int i = 1; i < 8; ++i) m = fmaxf(m, u[i]);
#pragma unroll
  for (int off = 32; off; off >>= 1) m = fmaxf(m, __shfl_xor(m, off));
  if (l == 0) red[w] = m;
  __syncthreads();
  m = fmaxf(fmaxf(red[0], red[1]), fmaxf(red[2], red[3]));
  __syncthreads();

  float p[8];
  float s = 0.f;
#pragma unroll
  for (int i = 0; i < 8; ++i) {
    p[i] = __builtin_amdgcn_exp2f((u[i] - m) * 1.4426950408889634f);
    s += p[i];
  }
#pragma unroll
  for (int off = 32; off; off >>= 1) s += __shfl_xor(s, off);
  if (l == 0) red[w] = s;
  __syncthreads();
  s = red[0] + red[1] + red[2] + red[3];

  const float inv = 1.0f / s;
#pragma unroll
  for (int i = 0; i < 8; ++i) alpha[b * S_ + t + i * 256] = p[i] * inv;
}

// ---------------------------------------------------------------------------
// out1[b,h] = sum_s alpha[b,s] * ei[b,s,h]. s split across 32 chunks/batch,
// fp32 atomics into the pre-zeroed output.
__global__ void k_agg(const unsigned short* __restrict__ ei, const float* __restrict__ alpha,
                      float* __restrict__ out1) {
  const int b = blockIdx.x >> 5;
  const int chunk = blockIdx.x & 31;
  const int l = threadIdx.x;      // block of 64 = 1 wave
  const int h0 = l << 3;
  const int s0 = chunk * 64;

  float acc[8] = {0.f, 0.f, 0.f, 0.f, 0.f, 0.f, 0.f, 0.f};
#pragma unroll 2
  for (int s = s0; s < s0 + 64; ++s) {
    const float a = alpha[b * S_ + s];
    bf16x8 e = *(const bf16x8*)(ei + ((size_t)(b * S_ + s)) * H_ + h0);
#pragma unroll
    for (int j = 0; j < 8; ++j) acc[j] += a * bf2f((unsigned short)e[j]);
  }
#pragma unroll
  for (int j = 0; j < 8; ++j) atomicAdd(&out1[b * H_ + h0 + j], acc[j]);
}

// ---------------------------------------------------------------------------
extern "C" void kernel_launch(void* const* d_in, const int* in_sizes, int n_in,
                              void* d_out, int out_size, void* d_ws, size_t ws_size,
                              hipStream_t stream) {
  const float* hidden = (const float*)d_in[0];
  const float* ctx    = (const float*)d_in[1];
  const void*  mask   = d_in[2];
  const float* Wd     = (const float*)d_in[3];
  const float* bd     = (const float*)d_in[4];
  const float* We     = (const float*)d_in[5];
  const float* be     = (const float*)d_in[6];
  const float* V      = (const float*)d_in[7];

  float* out   = (float*)d_out;
  float* alpha = out;               // [B,S] = 131072
  float* out1  = out + B_ * S_;     // [B,H] = 32768

  // ws layout: ei bf16 (128 MiB) | ui fp32 (512 KiB) | di fp32 (128 KiB) | flag
  char* ws = (char*)d_ws;
  unsigned short* ei = (unsigned short*)ws;
  float* ui = (float*)(ws + (size_t)B_ * S_ * H_ * 2);
  float* di = (float*)(ws + (size_t)B_ * S_ * H_ * 2 + (size_t)B_ * S_ * 4);
  int* flag = (int*)(ws + (size_t)B_ * S_ * H_ * 2 + (size_t)B_ * S_ * 4 + (size_t)B_ * H_ * 4);

  hipMemsetAsync(d_out, 0, (size_t)out_size * 4, stream);  // out1 accumulated via atomics
  hipMemsetAsync(flag, 0, 4, stream);

  k_detect<<<1, 256, 0, stream>>>((const unsigned int*)mask, flag);
  k_di<<<(B_ * H_) / 256, 256, 0, stream>>>(hidden, Wd, bd, di);
  k_ei_gemm<<<(B_ * S_) / BM, 256, 0, stream>>>(ctx, We, be, ei);
  k_ui<<<(B_ * S_) / 4, 256, 0, stream>>>(ei, di, V, mask, flag, ui);
  k_softmax<<<B_, 256, 0, stream>>>(ui, alpha);
  k_agg<<<B_ * 32, 64, 0, stream>>>(ei, alpha, out1);
}

// Round 2
// 320.650 us; speedup vs baseline: 1.1109x; 1.1109x over previous
//
#include <hip/hip_runtime.h>
#include <cstdint>

// Problem constants (B,S,D,H) from the reference
#define B_ 64
#define S_ 2048
#define D_ 512
#define H_ 512

using f32x4  = __attribute__((ext_vector_type(4))) float;
using bf16x8 = __attribute__((ext_vector_type(8))) short;

__device__ __forceinline__ unsigned short f2bf(float f) {
  unsigned u = __float_as_uint(f);
  u += 0x7FFFu + ((u >> 16) & 1u);   // round-to-nearest-even
  return (unsigned short)(u >> 16);
}
__device__ __forceinline__ float bf2f(unsigned short h) {
  return __uint_as_float(((unsigned)h) << 16);
}
// tanh via v_exp_f32: 1 - 2/(exp2(2x*log2e)+1); exact saturation at +-inf
__device__ __forceinline__ float fast_tanh(float x) {
  float t = __builtin_amdgcn_exp2f(x * 2.8853900817779268f);
  return 1.0f - 2.0f * __builtin_amdgcn_rcpf(t + 1.0f);
}

// async global->LDS, 16B per lane; LDS dest = wave-uniform base + lane*16
__device__ __forceinline__ void gl_lds16(const unsigned short* g, unsigned short* l) {
  __builtin_amdgcn_global_load_lds(
      (const __attribute__((address_space(1))) unsigned int*)g,
      (__attribute__((address_space(3))) unsigned int*)l, 16, 0, 0);
}

// ---------------------------------------------------------------------------
// Mask dtype detection (bool-bytes vs int32): int32 layout has zero bytes at
// offsets 4k+1..3. flag=0 -> int32 layout, flag=1 -> byte layout.
__global__ void k_detect(const unsigned int* __restrict__ mw, int* __restrict__ flag) {
  unsigned acc = 0;
  for (int k = threadIdx.x; k < (B_ * S_ / 4); k += 256)
    acc |= mw[k] & 0xFFFFFF00u;
  if (acc) atomicOr(flag, 1);
}

// ---------------------------------------------------------------------------
// fp32 -> bf16 pack, 8 elems/thread
__global__ void k_cvt(const float* __restrict__ src, unsigned short* __restrict__ dst, int n8) {
  int i = blockIdx.x * 256 + threadIdx.x;
  if (i >= n8) return;
  const f32x4* p = (const f32x4*)(src + (size_t)i * 8);
  f32x4 a = p[0], b = p[1];
  bf16x8 o;
  o[0] = (short)f2bf(a[0]); o[1] = (short)f2bf(a[1]);
  o[2] = (short)f2bf(a[2]); o[3] = (short)f2bf(a[3]);
  o[4] = (short)f2bf(b[0]); o[5] = (short)f2bf(b[1]);
  o[6] = (short)f2bf(b[2]); o[7] = (short)f2bf(b[3]);
  *(bf16x8*)(dst + (size_t)i * 8) = o;
}

// ---------------------------------------------------------------------------
// di[b,h] = hidden[b,:] . Wd[h,:] + bd[h]   (fp32, tiny)
__global__ void k_di(const float* __restrict__ hidden, const float* __restrict__ Wd,
                     const float* __restrict__ bd, float* __restrict__ di) {
  int idx = blockIdx.x * 256 + threadIdx.x;   // 32768 total
  int h = idx >> 6;
  int b = idx & 63;
  const f32x4* hp = (const f32x4*)(hidden + (size_t)b * D_);
  const f32x4* wp = (const f32x4*)(Wd + (size_t)h * D_);
  float acc = 0.f;
#pragma unroll 8
  for (int i = 0; i < D_ / 4; ++i) {
    f32x4 x = hp[i], y = wp[i];
    acc += x[0] * y[0] + x[1] * y[1] + x[2] * y[2] + x[3] * y[3];
  }
  di[b * H_ + h] = acc + bd[h];
}

// ---------------------------------------------------------------------------
// ei-GEMM (m97 structure) with FUSED ui partial sums; ei is never stored.
// A = ctx bf16 [131072 x 512], B = We bf16 [512 x 512] (both row-major, K inner).
// Grid 4096 = 1024 m-tiles x 4 n-tiles, XCD-chunk swizzled so the 4 blocks
// sharing an A panel run on the same XCD (L2 reuse).
// Block: 256 thr (4 waves, 2x2), tile 128x128, BK=32, 16x16x32 bf16 MFMA.
__global__ __launch_bounds__(256, 4) void k_ei_gemm(
    const unsigned short* __restrict__ A, const unsigned short* __restrict__ Bw,
    const float* __restrict__ be, const float* __restrict__ V,
    const float* __restrict__ di, float* __restrict__ ui) {
  __shared__ __align__(16) unsigned short ldsA[128 * 32];
  __shared__ __align__(16) unsigned short ldsB[128 * 32];

  const int bid = blockIdx.x;
  const int swz = (bid & 7) * 512 + (bid >> 3);   // bijective (4096 % 8 == 0)
  const int m   = swz >> 2;
  const int nt  = swz & 3;
  const int row0 = m << 7;
  const int col0 = nt << 7;

  const int t  = threadIdx.x;
  const int l  = t & 63;
  const int w  = t >> 6;
  const int wm = (w >> 1) << 6;
  const int wn = (w & 1) << 6;
  const int lr = l & 15;
  const int lg = l >> 4;

  // staging: wave w covers rows [w*32, w*32+32); lane l -> row +(l>>2), col8 (l&3)
  const int sr = l >> 2;
  const int sc = (l & 3) << 3;
  const unsigned short* gA = A + (size_t)(row0 + w * 32 + sr) * D_ + sc;
  const unsigned short* gB = Bw + (size_t)(col0 + w * 32 + sr) * D_ + sc;
  unsigned short* lA = ldsA + w * 1024;   // wave-uniform LDS base (linear [128][32])
  unsigned short* lB = ldsB + w * 1024;

  f32x4 acc[4][4];
  const f32x4 z = {0.f, 0.f, 0.f, 0.f};
#pragma unroll
  for (int mi = 0; mi < 4; ++mi)
#pragma unroll
    for (int ni = 0; ni < 4; ++ni) acc[mi][ni] = z;

  for (int kt = 0; kt < 16; ++kt) {
    const int k0 = kt << 5;
    gl_lds16(gA + k0, lA);
    gl_lds16(gA + 16 * D_ + k0, lA + 512);
    gl_lds16(gB + k0, lB);
    gl_lds16(gB + 16 * D_ + k0, lB + 512);
    asm volatile("s_waitcnt vmcnt(0)" ::: "memory");
    __syncthreads();

    bf16x8 af[4], bq[4];
#pragma unroll
    for (int mi = 0; mi < 4; ++mi)
      af[mi] = *(const bf16x8*)&ldsA[(wm + mi * 16 + lr) * 32 + (lg << 3)];
#pragma unroll
    for (int ni = 0; ni < 4; ++ni)
      bq[ni] = *(const bf16x8*)&ldsB[(wn + ni * 16 + lr) * 32 + (lg << 3)];
#pragma unroll
    for (int mi = 0; mi < 4; ++mi)
#pragma unroll
      for (int ni = 0; ni < 4; ++ni)
        acc[mi][ni] = __builtin_amdgcn_mfma_f32_16x16x32_bf16(
            af[mi], bq[ni], acc[mi][ni], 0, 0, 0);
    __syncthreads();
  }

  // fused ui partials: ui[row] += sum_{gc in tile} V[gc]*tanh(di[b,gc]+acc+be[gc])
  // C/D layout: col = lane&15 (lr), row = lg*4 + j within each 16x16 frag.
  const int b = row0 >> 11;   // BM=128 divides S=2048 -> block-uniform batch
  float uacc[4][4];
#pragma unroll
  for (int mi = 0; mi < 4; ++mi)
#pragma unroll
    for (int j = 0; j < 4; ++j) uacc[mi][j] = 0.f;

#pragma unroll
  for (int ni = 0; ni < 4; ++ni) {
    const int gc = col0 + wn + ni * 16 + lr;
    const float vv = V[gc];
    const float base = di[b * H_ + gc] + be[gc];
#pragma unroll
    for (int mi = 0; mi < 4; ++mi)
#pragma unroll
      for (int j = 0; j < 4; ++j)
        uacc[mi][j] += vv * fast_tanh(base + acc[mi][ni][j]);
  }
#pragma unroll
  for (int mi = 0; mi < 4; ++mi)
#pragma unroll
    for (int j = 0; j < 4; ++j) {
      float s = uacc[mi][j];
      s += __shfl_xor(s, 1);
      s += __shfl_xor(s, 2);
      s += __shfl_xor(s, 4);
      s += __shfl_xor(s, 8);
      if (lr == 0)
        atomicAdd(&ui[row0 + wm + mi * 16 + (lg << 2) + j], s);
    }
}

// ---------------------------------------------------------------------------
// softmax over S per batch row, applying mask -> -inf first
__global__ void k_softmax(const float* __restrict__ ui, const void* __restrict__ mask,
                          const int* __restrict__ flag, float* __restrict__ alpha) {
  __shared__ float red[4];
  const int b = blockIdx.x, t = threadIdx.x;
  const int l = t & 63, w = t >> 6;
  const int fl = *flag;

  float u[8];
#pragma unroll
  for (int i = 0; i < 8; ++i) {
    const int idx = b * S_ + t + i * 256;
    const int msk = fl ? (int)((const unsigned char*)mask)[idx]
                       : ((const int*)mask)[idx];
    u[i] = msk ? -__builtin_inff() : ui[idx];
  }

  float mx = u[0];
#pragma unroll
  for (int i = 1; i < 8; ++i) mx = fmaxf(mx, u[i]);
#pragma unroll
  for (int off = 32; off; off >>= 1) mx = fmaxf(mx, __shfl_xor(mx, off));
  if (l == 0) red[w] = mx;
  __syncthreads();
  mx = fmaxf(fmaxf(red[0], red[1]), fmaxf(red[2], red[3]));
  __syncthreads();

  float p[8];
  float s = 0.f;
#pragma unroll
  for (int i = 0; i < 8; ++i) {
    p[i] = __builtin_amdgcn_exp2f((u[i] - mx) * 1.4426950408889634f);
    s += p[i];
  }
#pragma unroll
  for (int off = 32; off; off >>= 1) s += __shfl_xor(s, off);
  if (l == 0) red[w] = s;
  __syncthreads();
  s = red[0] + red[1] + red[2] + red[3];

  const float inv = 1.0f / s;
#pragma unroll
  for (int i = 0; i < 8; ++i) alpha[b * S_ + t + i * 256] = p[i] * inv;
}

// ---------------------------------------------------------------------------
// wsum[b,d] = sum_s alpha[b,s] * ctxb[b,s,d]   (bf16 ctx, fp32 accum)
// grid = B*16 (128-s chunks), 256 thr; cross-wave LDS reduce then atomics.
__global__ void k_wsum(const unsigned short* __restrict__ ctxb, const float* __restrict__ alpha,
                       float* __restrict__ wsum) {
  __shared__ float red[3][512];
  const int b = blockIdx.x >> 4, chunk = blockIdx.x & 15;
  const int t = threadIdx.x;
  const int h0 = (t & 63) << 3;
  const int sw = t >> 6;
  const int s0 = chunk << 7;

  float acc[8] = {0.f, 0.f, 0.f, 0.f, 0.f, 0.f, 0.f, 0.f};
#pragma unroll 4
  for (int k = 0; k < 32; ++k) {
    const int s = s0 + sw + (k << 2);
    const float a = alpha[b * S_ + s];
    bf16x8 e = *(const bf16x8*)(ctxb + ((size_t)(b * S_ + s)) * D_ + h0);
#pragma unroll
    for (int j = 0; j < 8; ++j) acc[j] += a * bf2f((unsigned short)e[j]);
  }
  if (sw) {
#pragma unroll
    for (int j = 0; j < 8; ++j) red[sw - 1][h0 + j] = acc[j];
  }
  __syncthreads();
  if (sw == 0) {
#pragma unroll
    for (int j = 0; j < 8; ++j)
      atomicAdd(&wsum[b * D_ + h0 + j],
                acc[j] + red[0][h0 + j] + red[1][h0 + j] + red[2][h0 + j]);
  }
}

// ---------------------------------------------------------------------------
// out1[b,h] = wsum[b,:] . We[h,:] + be[h]   (fp32, tiny; Sum(alpha)=1 absorbs be)
__global__ void k_out1(const float* __restrict__ wsum, const float* __restrict__ We,
                       const float* __restrict__ be, float* __restrict__ out1) {
  int idx = blockIdx.x * 256 + threadIdx.x;   // 32768 total
  int h = idx >> 6;
  int b = idx & 63;
  const f32x4* wp = (const f32x4*)(wsum + (size_t)b * D_);
  const f32x4* ep = (const f32x4*)(We + (size_t)h * D_);
  float acc = 0.f;
#pragma unroll 8
  for (int i = 0; i < D_ / 4; ++i) {
    f32x4 x = wp[i], y = ep[i];
    acc += x[0] * y[0] + x[1] * y[1] + x[2] * y[2] + x[3] * y[3];
  }
  out1[b * H_ + h] = acc + be[h];
}

// ---------------------------------------------------------------------------
extern "C" void kernel_launch(void* const* d_in, const int* in_sizes, int n_in,
                              void* d_out, int out_size, void* d_ws, size_t ws_size,
                              hipStream_t stream) {
  const float* hidden = (const float*)d_in[0];
  const float* ctx    = (const float*)d_in[1];
  const void*  mask   = d_in[2];
  const float* Wd     = (const float*)d_in[3];
  const float* bd     = (const float*)d_in[4];
  const float* We     = (const float*)d_in[5];
  const float* be     = (const float*)d_in[6];
  const float* V      = (const float*)d_in[7];

  float* out   = (float*)d_out;
  float* alpha = out;               // [B,S]
  float* out1  = out + B_ * S_;     // [B,H]

  // ws layout: ctxb bf16 | ui | di | wsum | flag | pad | Web bf16
  char* ws = (char*)d_ws;
  const size_t off_ctxb = 0;
  const size_t off_ui   = off_ctxb + (size_t)B_ * S_ * D_ * 2;    // 134217728
  const size_t off_di   = off_ui + (size_t)B_ * S_ * 4;           // +524288
  const size_t off_wsum = off_di + (size_t)B_ * H_ * 4;           // +131072
  const size_t off_flag = off_wsum + (size_t)B_ * D_ * 4;         // +131072
  const size_t off_web  = (off_flag + 4 + 15) & ~(size_t)15;      // align 16

  unsigned short* ctxb = (unsigned short*)(ws + off_ctxb);
  float* ui   = (float*)(ws + off_ui);
  float* di   = (float*)(ws + off_di);
  float* wsum = (float*)(ws + off_wsum);
  int*   flag = (int*)(ws + off_flag);
  unsigned short* Web = (unsigned short*)(ws + off_web);

  // zero ui..flag (contiguous); atomics accumulate into ui and wsum
  hipMemsetAsync(ws + off_ui, 0, off_flag + 4 - off_ui, stream);

  k_detect<<<1, 256, 0, stream>>>((const unsigned int*)mask, flag);
  k_cvt<<<(B_ * S_ * D_ / 8 + 255) / 256, 256, 0, stream>>>(ctx, ctxb, B_ * S_ * D_ / 8);
  k_cvt<<<(H_ * D_ / 8 + 255) / 256, 256, 0, stream>>>(We, Web, H_ * D_ / 8);
  k_di<<<(B_ * H_) / 256, 256, 0, stream>>>(hidden, Wd, bd, di);
  k_ei_gemm<<<(B_ * S_ / 128) * 4, 256, 0, stream>>>(ctxb, Web, be, V, di, ui);
  k_softmax<<<B_, 256, 0, stream>>>(ui, mask, flag, alpha);
  k_wsum<<<B_ * 16, 256, 0, stream>>>(ctxb, alpha, wsum);
  k_out1<<<(B_ * H_) / 256, 256, 0, stream>>>(wsum, We, be, out1);
}

// Round 3
// 246.774 us; speedup vs baseline: 1.4435x; 1.2994x over previous
//
#include <hip/hip_runtime.h>
#include <cstdint>

// Problem constants (B,S,D,H) from the reference
#define B_ 64
#define S_ 2048
#define D_ 512
#define H_ 512

using f32x4  = __attribute__((ext_vector_type(4))) float;
using bf16x8 = __attribute__((ext_vector_type(8))) short;

__device__ __forceinline__ unsigned short f2bf(float f) {
  unsigned u = __float_as_uint(f);
  u += 0x7FFFu + ((u >> 16) & 1u);   // round-to-nearest-even
  return (unsigned short)(u >> 16);
}
__device__ __forceinline__ float bf2f(unsigned short h) {
  return __uint_as_float(((unsigned)h) << 16);
}
// tanh via v_exp_f32: 1 - 2/(exp2(2x*log2e)+1); exact saturation at +-inf
__device__ __forceinline__ float fast_tanh(float x) {
  float t = __builtin_amdgcn_exp2f(x * 2.8853900817779268f);
  return 1.0f - 2.0f * __builtin_amdgcn_rcpf(t + 1.0f);
}

// async global->LDS, 16B per lane; LDS dest = wave-uniform base + lane*16
__device__ __forceinline__ void gl_lds16(const unsigned short* g, unsigned short* l) {
  __builtin_amdgcn_global_load_lds(
      (const __attribute__((address_space(1))) unsigned int*)g,
      (__attribute__((address_space(3))) unsigned int*)l, 16, 0, 0);
}

// ---------------------------------------------------------------------------
// fp32 -> bf16 pack, 8 elems/thread
__global__ void k_cvt(const float* __restrict__ src, unsigned short* __restrict__ dst, int n8) {
  int i = blockIdx.x * 256 + threadIdx.x;
  if (i >= n8) return;
  const f32x4* p = (const f32x4*)(src + (size_t)i * 8);
  f32x4 a = p[0], b = p[1];
  bf16x8 o;
  o[0] = (short)f2bf(a[0]); o[1] = (short)f2bf(a[1]);
  o[2] = (short)f2bf(a[2]); o[3] = (short)f2bf(a[3]);
  o[4] = (short)f2bf(b[0]); o[5] = (short)f2bf(b[1]);
  o[6] = (short)f2bf(b[2]); o[7] = (short)f2bf(b[3]);
  *(bf16x8*)(dst + (size_t)i * 8) = o;
}

// ---------------------------------------------------------------------------
// di[b,h] = hidden[b,:] . Wd[h,:] + bd[h]   (fp32, tiny)
__global__ void k_di(const float* __restrict__ hidden, const float* __restrict__ Wd,
                     const float* __restrict__ bd, float* __restrict__ di) {
  int idx = blockIdx.x * 256 + threadIdx.x;   // 32768 total
  int h = idx >> 6;
  int b = idx & 63;
  const f32x4* hp = (const f32x4*)(hidden + (size_t)b * D_);
  const f32x4* wp = (const f32x4*)(Wd + (size_t)h * D_);
  float acc = 0.f;
#pragma unroll 8
  for (int i = 0; i < D_ / 4; ++i) {
    f32x4 x = hp[i], y = wp[i];
    acc += x[0] * y[0] + x[1] * y[1] + x[2] * y[2] + x[3] * y[3];
  }
  di[b * H_ + h] = acc + bd[h];
}

// ---------------------------------------------------------------------------
// ei-GEMM with fused ui partials, atomic-free.
// A = ctx bf16 [131072 x 512], B = We bf16 [512 x 512], 128x128 tile, BK=32.
// T3-minimal 2-phase: LDS double-buffer, STAGE(next) issued before compute(cur),
// one __syncthreads per k-step (implicit vmcnt(0) is the drain point).
// LDS slot swizzle (slot ^= (row>>1)&3) applied on the GLOBAL source per-lane
// (gl_lds dest must stay linear) and on the ds_read side -> 2-way banks (free).
// Output: ui4[nt][row] = partial sum over this nt's 128 columns (no atomics).
__global__ __launch_bounds__(256, 4) void k_ei_gemm(
    const unsigned short* __restrict__ A, const unsigned short* __restrict__ Bw,
    const float* __restrict__ be, const float* __restrict__ V,
    const float* __restrict__ di, float* __restrict__ ui4) {
  __shared__ __align__(16) unsigned short ldsA[2][128 * 32];
  __shared__ __align__(16) unsigned short ldsB[2][128 * 32];
  __shared__ float ured[4][64];

  const int bid = blockIdx.x;
  const int swz = (bid & 7) * 512 + (bid >> 3);   // bijective XCD chunking (4096%8==0)
  const int row0 = (swz >> 2) << 7;
  const int nt   = swz & 3;
  const int col0 = nt << 7;

  const int t  = threadIdx.x;
  const int l  = t & 63;
  const int w  = t >> 6;
  const int wm = (w >> 1) << 6;
  const int wn = (w & 1) << 6;
  const int lr = l & 15;
  const int lg = l >> 4;

  // staging: wave w rows [w*32, w*32+32); lane l -> row +(l>>2), swizzled chunk
  const int sr = l >> 2;
  const int sc = ((l & 3) ^ ((sr >> 1) & 3)) << 3;   // pre-swizzled global source
  const unsigned short* gA = A + (size_t)(row0 + w * 32 + sr) * D_ + sc;
  const unsigned short* gB = Bw + (size_t)(col0 + w * 32 + sr) * D_ + sc;
  unsigned short* lA[2] = {&ldsA[0][w * 1024], &ldsA[1][w * 1024]};
  unsigned short* lB[2] = {&ldsB[0][w * 1024], &ldsB[1][w * 1024]};

  // read-side swizzle: chunk lg of row r lives in slot lg ^ ((r>>1)&3); the
  // wm/wn/mi*16 parts are multiples of 16 so only lr enters the XOR.
  const int rslot = (lg ^ ((lr >> 1) & 3)) << 3;

#define STAGE(bf, kk) do {                      \
    const int k0_ = (kk) << 5;                  \
    gl_lds16(gA + k0_,           lA[bf]);       \
    gl_lds16(gA + 16 * D_ + k0_, lA[bf] + 512); \
    gl_lds16(gB + k0_,           lB[bf]);       \
    gl_lds16(gB + 16 * D_ + k0_, lB[bf] + 512); \
  } while (0)

  f32x4 acc[4][4];
  const f32x4 z = {0.f, 0.f, 0.f, 0.f};
#pragma unroll
  for (int mi = 0; mi < 4; ++mi)
#pragma unroll
    for (int ni = 0; ni < 4; ++ni) acc[mi][ni] = z;

  STAGE(0, 0);
  int cur = 0;
  for (int kt = 0; kt < 16; ++kt) {
    __syncthreads();                 // vmcnt(0)+barrier: buf[cur] ready, prev reads done
    if (kt < 15) STAGE(cur ^ 1, kt + 1);   // prefetch next under this step's compute

    bf16x8 af[4], bq[4];
#pragma unroll
    for (int mi = 0; mi < 4; ++mi)
      af[mi] = *(const bf16x8*)&ldsA[cur][(wm + mi * 16 + lr) * 32 + rslot];
#pragma unroll
    for (int ni = 0; ni < 4; ++ni)
      bq[ni] = *(const bf16x8*)&ldsB[cur][(wn + ni * 16 + lr) * 32 + rslot];
#pragma unroll
    for (int mi = 0; mi < 4; ++mi)
#pragma unroll
      for (int ni = 0; ni < 4; ++ni)
        acc[mi][ni] = __builtin_amdgcn_mfma_f32_16x16x32_bf16(
            af[mi], bq[ni], acc[mi][ni], 0, 0, 0);
    cur ^= 1;
  }
#undef STAGE

  // fused ui partials over this block's 128 columns; atomic-free.
  // C/D layout: col = lr, row = lg*4 + j within each 16x16 frag.
  const int b = row0 >> 11;   // BM=128 divides S=2048 -> block-uniform batch
  float uacc[4][4];
#pragma unroll
  for (int mi = 0; mi < 4; ++mi)
#pragma unroll
    for (int j = 0; j < 4; ++j) uacc[mi][j] = 0.f;

#pragma unroll
  for (int ni = 0; ni < 4; ++ni) {
    const int gc = col0 + wn + ni * 16 + lr;
    const float vv = V[gc];
    const float base = di[b * H_ + gc] + be[gc];
#pragma unroll
    for (int mi = 0; mi < 4; ++mi)
#pragma unroll
      for (int j = 0; j < 4; ++j)
        uacc[mi][j] += vv * fast_tanh(base + acc[mi][ni][j]);
  }
  // reduce across the 16 lr-lanes; lanes lr==0 (lg=0..3) hold row sums
#pragma unroll
  for (int mi = 0; mi < 4; ++mi)
#pragma unroll
    for (int j = 0; j < 4; ++j) {
      float s = uacc[mi][j];
      s += __shfl_xor(s, 1);
      s += __shfl_xor(s, 2);
      s += __shfl_xor(s, 4);
      s += __shfl_xor(s, 8);
      if (lr == 0) ured[w][mi * 16 + (lg << 2) + j] = s;
    }
  __syncthreads();
  if (t < 128) {
    const int r = t & 63, half = t >> 6;   // half 0: waves 0+1 (rows 0-63); 1: waves 2+3
    const float v = ured[half * 2][r] + ured[half * 2 + 1][r];
    ui4[nt * (B_ * S_) + row0 + half * 64 + r] = v;
  }
}

// ---------------------------------------------------------------------------
// softmax over S per batch row: sums the 4 ui partials, applies mask -> -inf.
// Mask dtype (bool-bytes vs int32) detected per block from word high-bytes
// (scan limited to first 128KB so it is in-bounds under both layouts).
__global__ void k_softmax(const float* __restrict__ ui4, const void* __restrict__ mask,
                          float* __restrict__ alpha) {
  __shared__ float red[4];
  __shared__ int sfl;
  const int b = blockIdx.x, t = threadIdx.x;
  const int l = t & 63, w = t >> 6;

  if (t == 0) sfl = 0;
  const unsigned int* mw = (const unsigned int*)mask;
  unsigned det = (mw[b * 512 + t] | mw[b * 512 + 256 + t]) & 0xFFFFFF00u;
  __syncthreads();
  if (det) atomicOr(&sfl, 1);
  __syncthreads();
  const int fl = sfl;   // 1 => byte layout

  float u[8];
#pragma unroll
  for (int i = 0; i < 8; ++i) {
    const int idx = b * S_ + t + i * 256;
    const int msk = fl ? (int)((const unsigned char*)mask)[idx]
                       : ((const int*)mask)[idx];
    const float uv = ui4[idx] + ui4[idx + B_ * S_] + ui4[idx + 2 * B_ * S_] +
                     ui4[idx + 3 * B_ * S_];
    u[i] = msk ? -__builtin_inff() : uv;
  }

  float mx = u[0];
#pragma unroll
  for (int i = 1; i < 8; ++i) mx = fmaxf(mx, u[i]);
#pragma unroll
  for (int off = 32; off; off >>= 1) mx = fmaxf(mx, __shfl_xor(mx, off));
  if (l == 0) red[w] = mx;
  __syncthreads();
  mx = fmaxf(fmaxf(red[0], red[1]), fmaxf(red[2], red[3]));
  __syncthreads();

  float p[8];
  float s = 0.f;
#pragma unroll
  for (int i = 0; i < 8; ++i) {
    p[i] = __builtin_amdgcn_exp2f((u[i] - mx) * 1.4426950408889634f);
    s += p[i];
  }
#pragma unroll
  for (int off = 32; off; off >>= 1) s += __shfl_xor(s, off);
  if (l == 0) red[w] = s;
  __syncthreads();
  s = red[0] + red[1] + red[2] + red[3];

  const float inv = 1.0f / s;
#pragma unroll
  for (int i = 0; i < 8; ++i) alpha[b * S_ + t + i * 256] = p[i] * inv;
}

// ---------------------------------------------------------------------------
// part[chunk][b][d] = sum over 128 s of alpha * ctxb   (atomic-free partials)
__global__ void k_wsum(const unsigned short* __restrict__ ctxb, const float* __restrict__ alpha,
                       float* __restrict__ part) {
  __shared__ float red[3][512];
  const int b = blockIdx.x >> 4, chunk = blockIdx.x & 15;
  const int t = threadIdx.x;
  const int h0 = (t & 63) << 3;
  const int sw = t >> 6;
  const int s0 = chunk << 7;

  float acc[8] = {0.f, 0.f, 0.f, 0.f, 0.f, 0.f, 0.f, 0.f};
#pragma unroll 4
  for (int k = 0; k < 32; ++k) {
    const int s = s0 + sw + (k << 2);
    const float a = alpha[b * S_ + s];
    bf16x8 e = *(const bf16x8*)(ctxb + ((size_t)(b * S_ + s)) * D_ + h0);
#pragma unroll
    for (int j = 0; j < 8; ++j) acc[j] += a * bf2f((unsigned short)e[j]);
  }
  if (sw) {
#pragma unroll
    for (int j = 0; j < 8; ++j) red[sw - 1][h0 + j] = acc[j];
  }
  __syncthreads();
  if (sw == 0) {
#pragma unroll
    for (int j = 0; j < 8; ++j)
      part[((chunk << 6) + b) * 512 + h0 + j] =
          acc[j] + red[0][h0 + j] + red[1][h0 + j] + red[2][h0 + j];
  }
}

// wsum[b,d] = sum over the 16 chunks (2 MB, L2-hot)
__global__ void k_collapse(const float* __restrict__ part, float* __restrict__ wsum) {
  const int i = blockIdx.x * 256 + threadIdx.x;   // 32768 = B*D
  const int b = i >> 9, d = i & 511;
  float s = 0.f;
#pragma unroll
  for (int c = 0; c < 16; ++c) s += part[((c << 6) + b) * 512 + d];
  wsum[i] = s;
}

// ---------------------------------------------------------------------------
// out1[b,h] = wsum[b,:] . We[h,:] + be[h]   (Sum(alpha)=1 absorbs be)
__global__ void k_out1(const float* __restrict__ wsum, const float* __restrict__ We,
                       const float* __restrict__ be, float* __restrict__ out1) {
  int idx = blockIdx.x * 256 + threadIdx.x;   // 32768 total
  int h = idx >> 6;
  int b = idx & 63;
  const f32x4* wp = (const f32x4*)(wsum + (size_t)b * D_);
  const f32x4* ep = (const f32x4*)(We + (size_t)h * D_);
  float acc = 0.f;
#pragma unroll 8
  for (int i = 0; i < D_ / 4; ++i) {
    f32x4 x = wp[i], y = ep[i];
    acc += x[0] * y[0] + x[1] * y[1] + x[2] * y[2] + x[3] * y[3];
  }
  out1[b * H_ + h] = acc + be[h];
}

// ---------------------------------------------------------------------------
extern "C" void kernel_launch(void* const* d_in, const int* in_sizes, int n_in,
                              void* d_out, int out_size, void* d_ws, size_t ws_size,
                              hipStream_t stream) {
  const float* hidden = (const float*)d_in[0];
  const float* ctx    = (const float*)d_in[1];
  const void*  mask   = d_in[2];
  const float* Wd     = (const float*)d_in[3];
  const float* bd     = (const float*)d_in[4];
  const float* We     = (const float*)d_in[5];
  const float* be     = (const float*)d_in[6];
  const float* V      = (const float*)d_in[7];

  float* out   = (float*)d_out;
  float* alpha = out;               // [B,S]
  float* out1  = out + B_ * S_;     // [B,H]

  // ws layout (regions reused across pipeline phases; everything written
  // before read, so no zero-init needed anywhere):
  //   [0, 134.2MB)  ctxb bf16
  //   [+2MB)        ui4 (gemm->softmax), then part (wsum->collapse)
  //   [+128KB)      di (di->gemm), then wsum (collapse->out1)
  //   [+512KB)      Web bf16
  char* ws = (char*)d_ws;
  const size_t off_ctxb = 0;
  const size_t off_u2   = off_ctxb + (size_t)B_ * S_ * D_ * 2;   // 134217728
  const size_t off_r3   = off_u2 + 4ull * B_ * S_ * 4;           // +2 MiB
  const size_t off_web  = off_r3 + (size_t)B_ * H_ * 4;          // +128 KiB

  unsigned short* ctxb = (unsigned short*)(ws + off_ctxb);
  float* ui4  = (float*)(ws + off_u2);
  float* part = (float*)(ws + off_u2);
  float* di   = (float*)(ws + off_r3);
  float* wsum = (float*)(ws + off_r3);
  unsigned short* Web = (unsigned short*)(ws + off_web);

  k_cvt<<<(B_ * S_ * D_ / 8) / 256, 256, 0, stream>>>(ctx, ctxb, B_ * S_ * D_ / 8);
  k_cvt<<<(H_ * D_ / 8) / 256, 256, 0, stream>>>(We, Web, H_ * D_ / 8);
  k_di<<<(B_ * H_) / 256, 256, 0, stream>>>(hidden, Wd, bd, di);
  k_ei_gemm<<<(B_ * S_ / 128) * 4, 256, 0, stream>>>(ctxb, Web, be, V, di, ui4);
  k_softmax<<<B_, 256, 0, stream>>>(ui4, mask, alpha);
  k_wsum<<<B_ * 16, 256, 0, stream>>>(ctxb, alpha, part);
  k_collapse<<<(B_ * D_) / 256, 256, 0, stream>>>(part, wsum);
  k_out1<<<(B_ * H_) / 256, 256, 0, stream>>>(wsum, We, be, out1);
}

// Round 4
// 238.973 us; speedup vs baseline: 1.4906x; 1.0326x over previous
//
#include <hip/hip_runtime.h>
#include <cstdint>

// Problem constants (B,S,D,H) from the reference
#define B_ 64
#define S_ 2048
#define D_ 512
#define H_ 512

using f32x4  = __attribute__((ext_vector_type(4))) float;
using bf16x8 = __attribute__((ext_vector_type(8))) short;

__device__ __forceinline__ unsigned short f2bf(float f) {
  unsigned u = __float_as_uint(f);
  u += 0x7FFFu + ((u >> 16) & 1u);   // round-to-nearest-even
  return (unsigned short)(u >> 16);
}
__device__ __forceinline__ float bf2f(unsigned short h) {
  return __uint_as_float(((unsigned)h) << 16);
}
// tanh via v_exp_f32: 1 - 2/(exp2(2x*log2e)+1); exact saturation at +-inf
__device__ __forceinline__ float fast_tanh(float x) {
  float t = __builtin_amdgcn_exp2f(x * 2.8853900817779268f);
  return 1.0f - 2.0f * __builtin_amdgcn_rcpf(t + 1.0f);
}

// async global->LDS, 16B per lane; LDS dest = wave-uniform base + lane*16
__device__ __forceinline__ void gl_lds16(const unsigned short* g, unsigned short* l) {
  __builtin_amdgcn_global_load_lds(
      (const __attribute__((address_space(1))) unsigned int*)g,
      (__attribute__((address_space(3))) unsigned int*)l, 16, 0, 0);
}

__device__ __forceinline__ void barrier_raw() {
  asm volatile("" ::: "memory");
  __builtin_amdgcn_s_barrier();
  asm volatile("" ::: "memory");
}

// ---------------------------------------------------------------------------
// fp32 -> bf16 pack, 8 elems/thread
__global__ void k_cvt(const float* __restrict__ src, unsigned short* __restrict__ dst, int n8) {
  int i = blockIdx.x * 256 + threadIdx.x;
  if (i >= n8) return;
  const f32x4* p = (const f32x4*)(src + (size_t)i * 8);
  f32x4 a = p[0], b = p[1];
  bf16x8 o;
  o[0] = (short)f2bf(a[0]); o[1] = (short)f2bf(a[1]);
  o[2] = (short)f2bf(a[2]); o[3] = (short)f2bf(a[3]);
  o[4] = (short)f2bf(b[0]); o[5] = (short)f2bf(b[1]);
  o[6] = (short)f2bf(b[2]); o[7] = (short)f2bf(b[3]);
  *(bf16x8*)(dst + (size_t)i * 8) = o;
}

// ---------------------------------------------------------------------------
// di[b,h] = hidden[b,:] . Wd[h,:] + bd[h]   (fp32, tiny)
__global__ void k_di(const float* __restrict__ hidden, const float* __restrict__ Wd,
                     const float* __restrict__ bd, float* __restrict__ di) {
  int idx = blockIdx.x * 256 + threadIdx.x;   // 32768 total
  int h = idx >> 6;
  int b = idx & 63;
  const f32x4* hp = (const f32x4*)(hidden + (size_t)b * D_);
  const f32x4* wp = (const f32x4*)(Wd + (size_t)h * D_);
  float acc = 0.f;
#pragma unroll 8
  for (int i = 0; i < D_ / 4; ++i) {
    f32x4 x = hp[i], y = wp[i];
    acc += x[0] * y[0] + x[1] * y[1] + x[2] * y[2] + x[3] * y[3];
  }
  di[b * H_ + h] = acc + bd[h];
}

// ---------------------------------------------------------------------------
// ei-GEMM with fused ui partials, atomic-free.
// A = ctx bf16 [131072 x 512], B = We bf16 [512 x 512].
// Tile 256x128, 8 waves (4M x 2N, 64x64 each), BK=32, 16 k-steps.
// Counted-vmcnt 2-tiles-in-flight pipeline with raw s_barrier (T3+T4):
//   prologue: STAGE(k0), STAGE(k1)          (3 gl_lds16 per thread per tile)
//   iter kt:  vmcnt(3) -> tile kt resident (own share), kt+1 stays in flight
//             s_barrier -> all waves' shares resident
//             ds_read frags, setprio(1), 16 MFMA, setprio(0)
//             s_barrier -> all waves done reading buf[kt&1]
//             STAGE(buf[kt&1], kt+2)
// Slot-XOR swizzle (slot ^= (row>>1)&3): applied on the per-lane GLOBAL source
// (gl_lds dest must stay linear) and re-applied on the ds_read side.
// Output: ui4[nt][row] partial sums (no atomics).
__global__ __launch_bounds__(512, 4) void k_ei_gemm(
    const unsigned short* __restrict__ A, const unsigned short* __restrict__ Bw,
    const float* __restrict__ be, const float* __restrict__ V,
    const float* __restrict__ di, float* __restrict__ ui4) {
  __shared__ __align__(16) unsigned short ldsA[2][256 * 32];
  __shared__ __align__(16) unsigned short ldsB[2][128 * 32];
  __shared__ float ured[8][64];

  const int bid = blockIdx.x;
  const int swz = (bid & 7) * 256 + (bid >> 3);   // bijective XCD chunking (2048%8==0)
  const int row0 = (swz >> 2) << 8;               // 512 m-tiles of 256 rows
  const int nt   = swz & 3;
  const int col0 = nt << 7;

  const int t  = threadIdx.x;
  const int l  = t & 63;
  const int w  = t >> 6;          // 8 waves
  const int wm = (w >> 1) << 6;   // 4 M-bands of 64
  const int wn = (w & 1) << 6;    // 2 N-halves of 64
  const int lr = l & 15;
  const int lg = l >> 4;

  // staging: each wave covers 16 rows per pass; lane l -> row w*16+(l>>2),
  // linear slot l&3; global source chunk pre-swizzled by ((row>>1)&3).
  // row = w*16 + (l>>2): (row>>1)&3 == ((l>>3)&3) for all w (w*8 % 4 == 0).
  const int sr = l >> 2;
  const int sc = ((l & 3) ^ ((l >> 3) & 3)) << 3;
  const unsigned short* gA = A + (size_t)(row0 + w * 16 + sr) * D_ + sc;   // rows 0-127
  const unsigned short* gB = Bw + (size_t)(col0 + w * 16 + sr) * D_ + sc;  // rows 0-127
  // pass 2 (rows 128-255 of A): +128 rows; (128>>1)&3 == 0 so same swizzle.

  // read-side swizzle: chunk lg of row r lives in slot lg ^ ((r>>1)&3); only
  // lr enters the XOR (wm/wn/mi*16 are multiples of 16).
  const int rslot = (lg ^ ((lr >> 1) & 3)) << 3;

#define STAGE(bf, kk) do {                                          \
    const int k0_ = (kk) << 5;                                      \
    gl_lds16(gA + k0_,            &ldsA[bf][w * 512]);              \
    gl_lds16(gA + 128 * D_ + k0_, &ldsA[bf][4096 + w * 512]);       \
    gl_lds16(gB + k0_,            &ldsB[bf][w * 512]);              \
  } while (0)

  f32x4 acc[4][4];
  const f32x4 z = {0.f, 0.f, 0.f, 0.f};
#pragma unroll
  for (int mi = 0; mi < 4; ++mi)
#pragma unroll
    for (int ni = 0; ni < 4; ++ni) acc[mi][ni] = z;

  STAGE(0, 0);
  STAGE(1, 1);

  for (int kt = 0; kt < 16; ++kt) {
    if (kt < 15)
      asm volatile("s_waitcnt vmcnt(3)" ::: "memory");   // tile kt retired; kt+1 in flight
    else
      asm volatile("s_waitcnt vmcnt(0)" ::: "memory");
    barrier_raw();                                        // all waves' shares resident

    const int bf = kt & 1;
    bf16x8 af[4], bq[4];
#pragma unroll
    for (int mi = 0; mi < 4; ++mi)
      af[mi] = *(const bf16x8*)&ldsA[bf][(wm + mi * 16 + lr) * 32 + rslot];
#pragma unroll
    for (int ni = 0; ni < 4; ++ni)
      bq[ni] = *(const bf16x8*)&ldsB[bf][(wn + ni * 16 + lr) * 32 + rslot];

    __builtin_amdgcn_s_setprio(1);
#pragma unroll
    for (int mi = 0; mi < 4; ++mi)
#pragma unroll
      for (int ni = 0; ni < 4; ++ni)
        acc[mi][ni] = __builtin_amdgcn_mfma_f32_16x16x32_bf16(
            af[mi], bq[ni], acc[mi][ni], 0, 0, 0);
    __builtin_amdgcn_s_setprio(0);

    barrier_raw();                                        // reads of buf[bf] done
    if (kt + 2 < 16) STAGE(bf, kt + 2);                   // refill freed slot
  }
#undef STAGE

  // fused ui partials over this block's 128 columns; atomic-free.
  // C/D layout: col = lr, row = lg*4 + j within each 16x16 frag.
  const int b = row0 >> 11;   // BM=256 divides S=2048 -> block-uniform batch
  float uacc[4][4];
#pragma unroll
  for (int mi = 0; mi < 4; ++mi)
#pragma unroll
    for (int j = 0; j < 4; ++j) uacc[mi][j] = 0.f;

#pragma unroll
  for (int ni = 0; ni < 4; ++ni) {
    const int gc = col0 + wn + ni * 16 + lr;
    const float vv = V[gc];
    const float base = di[b * H_ + gc] + be[gc];
#pragma unroll
    for (int mi = 0; mi < 4; ++mi)
#pragma unroll
      for (int j = 0; j < 4; ++j)
        uacc[mi][j] += vv * fast_tanh(base + acc[mi][ni][j]);
  }
  // reduce across the 16 lr-lanes; lanes lr==0 (lg=0..3) hold 4-row sums
#pragma unroll
  for (int mi = 0; mi < 4; ++mi)
#pragma unroll
    for (int j = 0; j < 4; ++j) {
      float s = uacc[mi][j];
      s += __shfl_xor(s, 1);
      s += __shfl_xor(s, 2);
      s += __shfl_xor(s, 4);
      s += __shfl_xor(s, 8);
      if (lr == 0) ured[w][mi * 16 + (lg << 2) + j] = s;
    }
  __syncthreads();
  if (t < 256) {
    const int band = t >> 6, r = t & 63;   // waves 2*band (wn=0) + 2*band+1 (wn=64)
    ui4[nt * (B_ * S_) + row0 + t] = ured[band * 2][r] + ured[band * 2 + 1][r];
  }
}

// ---------------------------------------------------------------------------
// softmax over S per batch row: sums the 4 ui partials, applies mask -> -inf.
// Mask dtype (bool-bytes vs int32) detected per block from word high-bytes
// (scan limited to first 128KB so it is in-bounds under both layouts).
__global__ void k_softmax(const float* __restrict__ ui4, const void* __restrict__ mask,
                          float* __restrict__ alpha) {
  __shared__ float red[4];
  __shared__ int sfl;
  const int b = blockIdx.x, t = threadIdx.x;
  const int l = t & 63, w = t >> 6;

  if (t == 0) sfl = 0;
  const unsigned int* mw = (const unsigned int*)mask;
  unsigned det = (mw[b * 512 + t] | mw[b * 512 + 256 + t]) & 0xFFFFFF00u;
  __syncthreads();
  if (det) atomicOr(&sfl, 1);
  __syncthreads();
  const int fl = sfl;   // 1 => byte layout

  float u[8];
#pragma unroll
  for (int i = 0; i < 8; ++i) {
    const int idx = b * S_ + t + i * 256;
    const int msk = fl ? (int)((const unsigned char*)mask)[idx]
                       : ((const int*)mask)[idx];
    const float uv = ui4[idx] + ui4[idx + B_ * S_] + ui4[idx + 2 * B_ * S_] +
                     ui4[idx + 3 * B_ * S_];
    u[i] = msk ? -__builtin_inff() : uv;
  }

  float mx = u[0];
#pragma unroll
  for (int i = 1; i < 8; ++i) mx = fmaxf(mx, u[i]);
#pragma unroll
  for (int off = 32; off; off >>= 1) mx = fmaxf(mx, __shfl_xor(mx, off));
  if (l == 0) red[w] = mx;
  __syncthreads();
  mx = fmaxf(fmaxf(red[0], red[1]), fmaxf(red[2], red[3]));
  __syncthreads();

  float p[8];
  float s = 0.f;
#pragma unroll
  for (int i = 0; i < 8; ++i) {
    p[i] = __builtin_amdgcn_exp2f((u[i] - mx) * 1.4426950408889634f);
    s += p[i];
  }
#pragma unroll
  for (int off = 32; off; off >>= 1) s += __shfl_xor(s, off);
  if (l == 0) red[w] = s;
  __syncthreads();
  s = red[0] + red[1] + red[2] + red[3];

  const float inv = 1.0f / s;
#pragma unroll
  for (int i = 0; i < 8; ++i) alpha[b * S_ + t + i * 256] = p[i] * inv;
}

// ---------------------------------------------------------------------------
// part[chunk][b][d] = sum over 128 s of alpha * ctxb   (atomic-free partials)
__global__ void k_wsum(const unsigned short* __restrict__ ctxb, const float* __restrict__ alpha,
                       float* __restrict__ part) {
  __shared__ float red[3][512];
  const int b = blockIdx.x >> 4, chunk = blockIdx.x & 15;
  const int t = threadIdx.x;
  const int h0 = (t & 63) << 3;
  const int sw = t >> 6;
  const int s0 = chunk << 7;

  float acc[8] = {0.f, 0.f, 0.f, 0.f, 0.f, 0.f, 0.f, 0.f};
#pragma unroll 4
  for (int k = 0; k < 32; ++k) {
    const int s = s0 + sw + (k << 2);
    const float a = alpha[b * S_ + s];
    bf16x8 e = *(const bf16x8*)(ctxb + ((size_t)(b * S_ + s)) * D_ + h0);
#pragma unroll
    for (int j = 0; j < 8; ++j) acc[j] += a * bf2f((unsigned short)e[j]);
  }
  if (sw) {
#pragma unroll
    for (int j = 0; j < 8; ++j) red[sw - 1][h0 + j] = acc[j];
  }
  __syncthreads();
  if (sw == 0) {
#pragma unroll
    for (int j = 0; j < 8; ++j)
      part[((chunk << 6) + b) * 512 + h0 + j] =
          acc[j] + red[0][h0 + j] + red[1][h0 + j] + red[2][h0 + j];
  }
}

// wsum[b,d] = sum over the 16 chunks (2 MB, L2-hot)
__global__ void k_collapse(const float* __restrict__ part, float* __restrict__ wsum) {
  const int i = blockIdx.x * 256 + threadIdx.x;   // 32768 = B*D
  const int b = i >> 9, d = i & 511;
  float s = 0.f;
#pragma unroll
  for (int c = 0; c < 16; ++c) s += part[((c << 6) + b) * 512 + d];
  wsum[i] = s;
}

// ---------------------------------------------------------------------------
// out1[b,h] = wsum[b,:] . We[h,:] + be[h]   (Sum(alpha)=1 absorbs be)
__global__ void k_out1(const float* __restrict__ wsum, const float* __restrict__ We,
                       const float* __restrict__ be, float* __restrict__ out1) {
  int idx = blockIdx.x * 256 + threadIdx.x;   // 32768 total
  int h = idx >> 6;
  int b = idx & 63;
  const f32x4* wp = (const f32x4*)(wsum + (size_t)b * D_);
  const f32x4* ep = (const f32x4*)(We + (size_t)h * D_);
  float acc = 0.f;
#pragma unroll 8
  for (int i = 0; i < D_ / 4; ++i) {
    f32x4 x = wp[i], y = ep[i];
    acc += x[0] * y[0] + x[1] * y[1] + x[2] * y[2] + x[3] * y[3];
  }
  out1[b * H_ + h] = acc + be[h];
}

// ---------------------------------------------------------------------------
extern "C" void kernel_launch(void* const* d_in, const int* in_sizes, int n_in,
                              void* d_out, int out_size, void* d_ws, size_t ws_size,
                              hipStream_t stream) {
  const float* hidden = (const float*)d_in[0];
  const float* ctx    = (const float*)d_in[1];
  const void*  mask   = d_in[2];
  const float* Wd     = (const float*)d_in[3];
  const float* bd     = (const float*)d_in[4];
  const float* We     = (const float*)d_in[5];
  const float* be     = (const float*)d_in[6];
  const float* V      = (const float*)d_in[7];

  float* out   = (float*)d_out;
  float* alpha = out;               // [B,S]
  float* out1  = out + B_ * S_;     // [B,H]

  // ws layout (regions reused across pipeline phases; everything written
  // before read, so no zero-init needed anywhere):
  //   [0, 134.2MB)  ctxb bf16
  //   [+2MB)        ui4 (gemm->softmax), then part (wsum->collapse)
  //   [+128KB)      di (di->gemm), then wsum (collapse->out1)
  //   [+512KB)      Web bf16
  char* ws = (char*)d_ws;
  const size_t off_ctxb = 0;
  const size_t off_u2   = off_ctxb + (size_t)B_ * S_ * D_ * 2;   // 134217728
  const size_t off_r3   = off_u2 + 4ull * B_ * S_ * 4;           // +2 MiB
  const size_t off_web  = off_r3 + (size_t)B_ * H_ * 4;          // +128 KiB

  unsigned short* ctxb = (unsigned short*)(ws + off_ctxb);
  float* ui4  = (float*)(ws + off_u2);
  float* part = (float*)(ws + off_u2);
  float* di   = (float*)(ws + off_r3);
  float* wsum = (float*)(ws + off_r3);
  unsigned short* Web = (unsigned short*)(ws + off_web);

  k_cvt<<<(B_ * S_ * D_ / 8) / 256, 256, 0, stream>>>(ctx, ctxb, B_ * S_ * D_ / 8);
  k_cvt<<<(H_ * D_ / 8) / 256, 256, 0, stream>>>(We, Web, H_ * D_ / 8);
  k_di<<<(B_ * H_) / 256, 256, 0, stream>>>(hidden, Wd, bd, di);
  k_ei_gemm<<<(B_ * S_ / 256) * 4, 512, 0, stream>>>(ctxb, Web, be, V, di, ui4);
  k_softmax<<<B_, 256, 0, stream>>>(ui4, mask, alpha);
  k_wsum<<<B_ * 16, 256, 0, stream>>>(ctxb, alpha, part);
  k_collapse<<<(B_ * D_) / 256, 256, 0, stream>>>(part, wsum);
  k_out1<<<(B_ * H_) / 256, 256, 0, stream>>>(wsum, We, be, out1);
}